// Round 4
// baseline (76541.693 us; speedup 1.0000x reference)
//
#include <hip/hip_runtime.h>
#include <hip/hip_bf16.h>
#include <stdint.h>

// ---------------------------------------------------------------------------
// 2-layer LSTM + linear + CRF NLL on MI355X.
// Round 12: cut the h-broadcast fabric traffic 4x. Evidence: R9-R11 all
// neutral at ~19.5us/step while per-step IC read volume stayed 48MB
// (256 blocks x full h vectors); implied fabric BW ~2.5TB/s across three
// different access schemes => VOLUME-bound, not latency/sync-bound
// (R11 instrumentation: L1 waits only ~37%, L0 ~0%).
// Changes:
//  - 32 blocks/layer x 32 cols (was 128 x 8): h traffic 48 -> 12 MB/step.
//  - Weights stream from per-XCD L2 (read-only), pre-repacked ONCE into
//    fragment-linear per-block streams (repack_w kernel).
//  - k-PERMUTED fragment layout for Whh0/Whh1/Wih1 (+ fcw) so each lane's
//    8 gate outputs are position-contiguous: ring/h1_all store = one 16B
//    store per lane, no shuffles. MFMA is layout-agnostic as long as A and
//    B agree on the within-chunk k-mapping; x path keeps natural layout.
//  - Keep proven R10/R11 sync skeleton: 4-deep rings, split waits,
//    sc1 ring IO, direct-poll flags (now 32/layer).
// ---------------------------------------------------------------------------

typedef __bf16 bf16x8 __attribute__((ext_vector_type(8)));
typedef float f32x4 __attribute__((ext_vector_type(4)));
typedef unsigned u32x4 __attribute__((ext_vector_type(4)));

__device__ __forceinline__ f32x4 mfma16(bf16x8 a, bf16x8 b, f32x4 c) {
  return __builtin_amdgcn_mfma_f32_16x16x32_bf16(a, b, c, 0, 0, 0);
}

__device__ __forceinline__ unsigned short f2bf(float f) {
  unsigned u = __float_as_uint(f);
  u = u + 0x7fffu + ((u >> 16) & 1u);
  return (unsigned short)(u >> 16);
}
__device__ __forceinline__ float sigf(float x) { return 1.f / (1.f + __expf(-x)); }
__device__ __forceinline__ float tanh_s(float x) {
  float a = fabsf(x);
  float e = __expf(2.f * a);
  float r = 1.f - 2.f / (e + 1.f);
  return copysignf(r, x);
}
__device__ __forceinline__ bf16x8 cvt8(const float* p) {
  float4 a = *(const float4*)p;
  float4 b = *(const float4*)(p + 4);
  union { bf16x8 v; unsigned short u[8]; } r;
  r.u[0] = f2bf(a.x); r.u[1] = f2bf(a.y); r.u[2] = f2bf(a.z); r.u[3] = f2bf(a.w);
  r.u[4] = f2bf(b.x); r.u[5] = f2bf(b.y); r.u[6] = f2bf(b.z); r.u[7] = f2bf(b.w);
  return r.v;
}

// ---- agent-scope (IC-coherent) primitives ----
__device__ __forceinline__ unsigned ald32(const unsigned* p) {
  return __hip_atomic_load(p, __ATOMIC_RELAXED, __HIP_MEMORY_SCOPE_AGENT);
}
__device__ __forceinline__ unsigned long long ald64(const void* p) {
  return __hip_atomic_load((const unsigned long long*)p, __ATOMIC_RELAXED,
                           __HIP_MEMORY_SCOPE_AGENT);
}
__device__ __forceinline__ void ast32(void* p, unsigned v) {
  __hip_atomic_store((unsigned*)p, v, __ATOMIC_RELAXED, __HIP_MEMORY_SCOPE_AGENT);
}
__device__ __forceinline__ bf16x8 ldh(const unsigned short* p) {  // 16B via 2x8B IC loads
  union { bf16x8 v; unsigned long long q[2]; } u;
  u.q[0] = ald64(p);
  u.q[1] = ald64(p + 4);
  return u.v;
}
__device__ __forceinline__ void st16_sc1(void* p, u32x4 v) {
  asm volatile("global_store_dwordx4 %0, %1, off sc1" :: "v"(p), "v"(v) : "memory");
}

__device__ __forceinline__ unsigned wave_min(unsigned v) {
#pragma unroll
  for (int o = 32; o > 0; o >>= 1) {
    unsigned t = (unsigned)__shfl_xor((int)v, o);
    v = t < v ? t : v;
  }
  return v;
}

// ---------------------------------------------------------------------------
__global__ void fallback_k(float* out, unsigned wsmb) { *out = -(float)wsmb; }

__global__ void cvt_bf16(const float* __restrict__ in, unsigned short* __restrict__ out, int n) {
  int i = (blockIdx.x * 256 + threadIdx.x) * 4;
  if (i < n) {
    float4 v = *(const float4*)(in + i);
    ushort4 o;
    o.x = f2bf(v.x); o.y = f2bf(v.y); o.z = f2bf(v.z); o.w = f2bf(v.w);
    *(ushort4*)(out + i) = o;
  }
}

__global__ void add_vec(const float* __restrict__ a, const float* __restrict__ b,
                        float* __restrict__ o, int n) {
  int i = blockIdx.x * 256 + threadIdx.x;
  if (i < n) o[i] = a[i] + b[i];
}

// ---------------------------------------------------------------------------
// Repack fp32 weight [4096 rows][K] into per-block fragment streams (bf16).
// frag index f = ((bid*NKS + ks)*8 + mi)*64 + ln, 16B each.
// A-frag lane ln: m = ln&15 -> (gate=m&3, jj=m>>2); row = gate*1024 +
// bid*32 + mi*4 + jj; k chunk base = ks*32, group g = ln>>4.
// perm=0 (natural, x path):   k = ks*32 + g*8 + e
// perm=1 (ring-layout match): k = ks*32 + e*4 + g
__global__ void repack_w(const float* __restrict__ in, unsigned short* __restrict__ out,
                         int K, int ksshift, int perm) {
  int f = blockIdx.x * 256 + threadIdx.x;
  int NKS = 1 << ksshift;
  int total = 32 * NKS * 8 * 64;
  if (f >= total) return;
  int ln = f & 63;
  int t = f >> 6;
  int mi = t & 7; t >>= 3;
  int ks = t & (NKS - 1);
  int bid = t >> ksshift;
  int m = ln & 15;
  long row = (long)(m & 3) * 1024 + bid * 32 + mi * 4 + (m >> 2);
  const float* src = in + row * K + ks * 32;
  int g = ln >> 4;
  unsigned short o[8];
  if (perm) {
#pragma unroll
    for (int e = 0; e < 8; ++e) o[e] = f2bf(src[g + 4 * e]);
  } else {
#pragma unroll
    for (int e = 0; e < 8; ++e) o[e] = f2bf(src[g * 8 + e]);
  }
  *(ushort4*)(out + (long)f * 8) = *(ushort4*)o;
  *(ushort4*)(out + (long)f * 8 + 4) = *(ushort4*)(o + 4);
}

// fcw permuted+cvt so emis_k (unchanged) matches h1's permuted k layout:
// position p holds col (p&~31) + (p&7)*4 + ((p>>3)&3).
__global__ void perm_fcw(const float* __restrict__ in, unsigned short* __restrict__ out) {
  int i = blockIdx.x * 256 + threadIdx.x;
  if (i < 20480) {
    int n = i >> 10, p = i & 1023;
    int col = (p & ~31) + ((p & 7) << 2) + ((p >> 3) & 3);
    out[i] = f2bf(in[n * 1024 + col]);
  }
}

// ---------------------------------------------------------------------------
// Fused 2-layer persistent scan. 32 blocks/layer x 32 cols. Weights stream
// from L2 (fragment-linear). Ring: [4 slabs][64][1024] bf16 (permuted k
// layout within 32-col blocks). Flags (monotonic): 1=init, s+2=step s done.
// Waits: L0 s: own>=s+1, other>=s-2 (s>=4). L1 s: own>=s+1, then other>=s+2.
__global__ __launch_bounds__(256, 1) void lstm_fused(
    const float* __restrict__ x,              // [64][512][512] fp32 (fallback)
    const unsigned short* __restrict__ xb,    // [64][512][512] bf16 (or null)
    const unsigned short* __restrict__ WH0f, const unsigned short* __restrict__ WI0f,
    const unsigned short* __restrict__ WH1f, const unsigned short* __restrict__ WI1f,
    const float* __restrict__ bias0, const float* __restrict__ bias1,
    unsigned short* __restrict__ h1_all,      // [64][512][1024] bf16 (permuted)
    unsigned short* h0r, unsigned short* h1r, // [4][64][1024] rings
    unsigned* flags)   // [0..31]=L0 arrivals, [128..159]=L1 arrivals
{
  const int tid = threadIdx.x;
  const int lane = tid & 63;
  const int w = tid >> 6;            // wave = 16-batch tile
  const int c16 = lane & 15, rg = lane >> 4;
  const bool is1 = blockIdx.x >= 32;
  const int bid = (int)blockIdx.x & 31;
  const int j0 = bid * 32;
  unsigned* fown = flags + (is1 ? 128 : 0);
  unsigned* foth = flags + (is1 ? 0 : 128);

  const unsigned short* WH = (is1 ? WH1f : WH0f) + (size_t)bid * 131072;
  const unsigned short* WI = is1 ? (WI1f + (size_t)bid * 131072)
                                 : (WI0f + (size_t)bid * 65536);
  const float* bias = is1 ? bias1 : bias0;
  float bs[8][4];
#pragma unroll
  for (int mi = 0; mi < 8; ++mi)
#pragma unroll
    for (int r = 0; r < 4; ++r) bs[mi][r] = bias[r * 1024 + j0 + mi * 4 + rg];

  // ---- zero own slice of slab 3 (read as h[-1]): 64 batches x 32 cols ----
  unsigned short* ring = is1 ? h1r : h0r;
  {
    int bb = tid >> 2, q = tid & 3;
    u32x4 z = {0u, 0u, 0u, 0u};
    st16_sc1(ring + 3 * 65536 + bb * 1024 + j0 + q * 8, z);
  }
  asm volatile("s_waitcnt vmcnt(0)" ::: "memory");
  __syncthreads();
  if (tid == 0) ast32(fown + bid, 1u);

  const int b = w * 16 + c16;
  const int boff = b * 1024;
  const int ko = rg * 8;
  float cst[8];
#pragma unroll
  for (int mi = 0; mi < 8; ++mi) cst[mi] = 0.f;

  if (!is1) {
    // ================= layer 0 =================
    for (int s = 0; s < 512; ++s) {
      f32x4 acc[8];
#pragma unroll
      for (int mi = 0; mi < 8; ++mi) {
        f32x4 a;
        a[0] = bs[mi][0]; a[1] = bs[mi][1]; a[2] = bs[mi][2]; a[3] = bs[mi][3];
        acc[mi] = a;
      }
      // ---- x-part (no cross-block dep; before the wait) ----
      if (xb) {
        const unsigned short* xp = xb + ((long)b * 512 + s) * 512 + ko;
#pragma unroll
        for (int ks = 0; ks < 16; ++ks) {
          bf16x8 xv = *(const bf16x8*)(xp + ks * 32);
#pragma unroll
          for (int mi = 0; mi < 8; ++mi)
            acc[mi] = mfma16(*(const bf16x8*)(WI + ((ks * 8 + mi) * 64 + lane) * 8),
                             xv, acc[mi]);
        }
      } else {
        const float* xp = x + ((long)b * 512 + s) * 512 + ko;
#pragma unroll
        for (int ks = 0; ks < 16; ++ks) {
          bf16x8 xv = cvt8(xp + ks * 32);
#pragma unroll
          for (int mi = 0; mi < 8; ++mi)
            acc[mi] = mfma16(*(const bf16x8*)(WI + ((ks * 8 + mi) * 64 + lane) * 8),
                             xv, acc[mi]);
        }
      }
      // ---- wait: wave0 own layer, wave1 other layer (slab-reuse gate) ----
      const unsigned t_own = (unsigned)(s + 1);
      const unsigned t_oth = (s >= 4) ? (unsigned)(s - 2) : 0u;
      if (w == 0) {
        for (;;) {
          unsigned a = (lane < 32) ? ald32(fown + lane) : 0xFFFFFFFFu;
          if (wave_min(a) >= t_own) break;
          __builtin_amdgcn_s_sleep(1);
        }
      } else if (w == 1 && t_oth) {
        for (;;) {
          unsigned a = (lane < 32) ? ald32(foth + lane) : 0xFFFFFFFFu;
          if (wave_min(a) >= t_oth) break;
          __builtin_amdgcn_s_sleep(1);
        }
      }
      __syncthreads();
      __atomic_signal_fence(__ATOMIC_ACQ_REL);

      // ---- h-part ----
      const unsigned short* hp = ring + ((s + 3) & 3) * 65536 + boff + ko;
      bf16x8 hfr[32];
#pragma unroll
      for (int ks = 0; ks < 32; ++ks) hfr[ks] = ldh(hp + ks * 32);
#pragma unroll
      for (int ks = 0; ks < 32; ++ks) {
#pragma unroll
        for (int mi = 0; mi < 8; ++mi)
          acc[mi] = mfma16(*(const bf16x8*)(WH + ((ks * 8 + mi) * 64 + lane) * 8),
                           hfr[ks], acc[mi]);
      }
      // ---- gates; contiguous 16B store (permuted layout, no shuffles) ----
      unsigned huv[8];
#pragma unroll
      for (int mi = 0; mi < 8; ++mi) {
        float iv = sigf(acc[mi][0]);
        float fv = sigf(acc[mi][1]);
        float gv = tanh_s(acc[mi][2]);
        float ov = sigf(acc[mi][3]);
        float cn = fv * cst[mi] + iv * gv;
        cst[mi] = cn;
        huv[mi] = (unsigned)f2bf(ov * tanh_s(cn));
      }
      u32x4 v;
      v[0] = huv[0] | (huv[1] << 16);
      v[1] = huv[2] | (huv[3] << 16);
      v[2] = huv[4] | (huv[5] << 16);
      v[3] = huv[6] | (huv[7] << 16);
      st16_sc1(ring + (s & 3) * 65536 + boff + j0 + ko, v);
      asm volatile("s_waitcnt vmcnt(0)" ::: "memory");
      __syncthreads();
      if (tid == 0) ast32(fown + bid, (unsigned)(s + 2));
    }
  } else {
    // ================= layer 1 =================
    for (int s = 0; s < 512; ++s) {
      f32x4 acc[8];
#pragma unroll
      for (int mi = 0; mi < 8; ++mi) {
        f32x4 a;
        a[0] = bs[mi][0]; a[1] = bs[mi][1]; a[2] = bs[mi][2]; a[3] = bs[mi][3];
        acc[mi] = a;
      }
      // ---- wait A: own layer (read h1[s-1]) ----
      const unsigned t_own = (unsigned)(s + 1);
      if (w == 0) {
        for (;;) {
          unsigned a = (lane < 32) ? ald32(fown + lane) : 0xFFFFFFFFu;
          if (wave_min(a) >= t_own) break;
          __builtin_amdgcn_s_sleep(1);
        }
      }
      __syncthreads();
      __atomic_signal_fence(__ATOMIC_ACQ_REL);
      {
        const unsigned short* hp = ring + ((s + 3) & 3) * 65536 + boff + ko;
        bf16x8 hfr[32];
#pragma unroll
        for (int ks = 0; ks < 32; ++ks) hfr[ks] = ldh(hp + ks * 32);
#pragma unroll
        for (int ks = 0; ks < 32; ++ks) {
#pragma unroll
          for (int mi = 0; mi < 8; ++mi)
            acc[mi] = mfma16(*(const bf16x8*)(WH + ((ks * 8 + mi) * 64 + lane) * 8),
                             hfr[ks], acc[mi]);
        }
      }
      // ---- wait B: L0 finished step s (Whh1 compute overlapped above) ----
      const unsigned t_oth = (unsigned)(s + 2);
      if (w == 0) {
        for (;;) {
          unsigned a = (lane < 32) ? ald32(foth + lane) : 0xFFFFFFFFu;
          if (wave_min(a) >= t_oth) break;
          __builtin_amdgcn_s_sleep(1);
        }
      }
      __syncthreads();
      __atomic_signal_fence(__ATOMIC_ACQ_REL);
      {
        const unsigned short* hp = h0r + (s & 3) * 65536 + boff + ko;
        bf16x8 hfr[32];
#pragma unroll
        for (int ks = 0; ks < 32; ++ks) hfr[ks] = ldh(hp + ks * 32);
#pragma unroll
        for (int ks = 0; ks < 32; ++ks) {
#pragma unroll
          for (int mi = 0; mi < 8; ++mi)
            acc[mi] = mfma16(*(const bf16x8*)(WI + ((ks * 8 + mi) * 64 + lane) * 8),
                             hfr[ks], acc[mi]);
        }
      }
      // ---- gates; contiguous 16B stores ----
      unsigned huv[8];
#pragma unroll
      for (int mi = 0; mi < 8; ++mi) {
        float iv = sigf(acc[mi][0]);
        float fv = sigf(acc[mi][1]);
        float gv = tanh_s(acc[mi][2]);
        float ov = sigf(acc[mi][3]);
        float cn = fv * cst[mi] + iv * gv;
        cst[mi] = cn;
        huv[mi] = (unsigned)f2bf(ov * tanh_s(cn));
      }
      u32x4 v;
      v[0] = huv[0] | (huv[1] << 16);
      v[1] = huv[2] | (huv[3] << 16);
      v[2] = huv[4] | (huv[5] << 16);
      v[3] = huv[6] | (huv[7] << 16);
      st16_sc1(ring + (s & 3) * 65536 + boff + j0 + ko, v);
      *(u32x4*)(h1_all + ((long)b * 512 + s) * 1024 + j0 + ko) = v;
      asm volatile("s_waitcnt vmcnt(0)" ::: "memory");
      __syncthreads();
      if (tid == 0) ast32(fown + bid, (unsigned)(s + 2));
    }
  }
}

// ---------------------------------------------------------------------------
// emissions[m][c] = h1[m][:] . fc_w[c][:] + fc_b[c], c<20 (N padded to 32).
// h1 and fcw_b are in the SAME permuted k layout -> contraction unchanged.
__global__ __launch_bounds__(256) void emis_k(
    const unsigned short* __restrict__ h1, const unsigned short* __restrict__ fcw,
    const float* __restrict__ fcb, float* __restrict__ em) {
  __shared__ __align__(16) unsigned short Bsm[32768];
  const int tid = threadIdx.x;
  const int lane = tid & 63;
  const int w = tid >> 6;
  const int c16 = lane & 15, rg = lane >> 4;
  for (int u = tid; u < 4096; u += 256) {
    int tile = u >> 11;
    int ks = (u >> 6) & 31;
    int ln = u & 63;
    int n = tile * 16 + (ln & 15);
    int kb = ks * 32 + (ln >> 4) * 8;
    if (n < 20) {
      *(bf16x8*)&Bsm[u * 8] = *(const bf16x8*)(fcw + (long)n * 1024 + kb);
    } else {
#pragma unroll
      for (int j = 0; j < 8; ++j) Bsm[u * 8 + j] = 0;
    }
  }
  __syncthreads();
  const long r0 = (long)blockIdx.x * 64;
  const bf16x8* arow = (const bf16x8*)(h1 + (r0 + w * 16 + c16) * 1024 + rg * 8);
  const f32x4 fz = {0.f, 0.f, 0.f, 0.f};
  f32x4 acc0 = fz, acc1 = fz;
#pragma unroll 4
  for (int ks = 0; ks < 32; ++ks) {
    bf16x8 a = arow[ks * 4];
    acc0 = mfma16(a, *(const bf16x8*)&Bsm[(ks * 64 + lane) * 8], acc0);
    acc1 = mfma16(a, *(const bf16x8*)&Bsm[((32 + ks) * 64 + lane) * 8], acc1);
  }
#pragma unroll
  for (int r = 0; r < 4; ++r) {
    long row = r0 + w * 16 + rg * 4 + r;
    em[row * 20 + c16] = acc0[r] + fcb[c16];
    int col1 = 16 + c16;
    if (col1 < 20) em[row * 20 + col1] = acc1[r] + fcb[col1];
  }
}

// ---------------------------------------------------------------------------
// CRF NLL: one wave per batch. Lanes 0..19 hold alpha[j]; 511 serial steps.
__global__ __launch_bounds__(256) void crf_k(
    const float* __restrict__ em, const int* __restrict__ labels,
    const float* __restrict__ startt, const float* __restrict__ endt,
    const float* __restrict__ trans, float* __restrict__ out) {
  const int lane = threadIdx.x & 63;
  const int b = blockIdx.x * 4 + (threadIdx.x >> 6);
  const float NEG = -1e30f;
  const int j = lane;
  const bool act = j < 20;
  float treg[20];
#pragma unroll
  for (int i = 0; i < 20; ++i) treg[i] = act ? trans[i * 20 + j] : 0.f;
  const float* emb = em + (long)b * 512 * 20;
  const int* lab = labels + (long)b * 512;
  float alpha = act ? (startt[j] + emb[j]) : NEG;
  for (int t = 1; t < 512; ++t) {
    float mx = NEG;
#pragma unroll
    for (int i = 0; i < 20; ++i) {
      float v = __shfl(alpha, i) + treg[i];
      mx = fmaxf(mx, v);
    }
    float s = 0.f;
#pragma unroll
    for (int i = 0; i < 20; ++i) {
      float v = __shfl(alpha, i) + treg[i];
      s += __expf(v - mx);
    }
    bool m = lab[t] != -1;
    float na = emb[t * 20 + (act ? j : 0)] + mx + __logf(s);
    if (act && m) alpha = na;
  }
  float v = act ? (alpha + endt[j]) : NEG;
  float mx = v;
#pragma unroll
  for (int o = 32; o > 0; o >>= 1) mx = fmaxf(mx, __shfl_xor(mx, o));
  float s = act ? __expf(v - mx) : 0.f;
#pragma unroll
  for (int o = 32; o > 0; o >>= 1) s += __shfl_xor(s, o);
  float logZ = mx + __logf(s);
  float part = 0.f;
  int cntm = 0;
  for (int t = lane; t < 512; t += 64) cntm += (lab[t] != -1) ? 1 : 0;
  for (int t = 1 + lane; t < 512; t += 64) {
    int tg = lab[t];
    if (tg != -1) {
      int tp = lab[t - 1];
      int tgc = min(max(tg, 0), 19);
      int tpc = min(max(tp, 0), 19);
      part += trans[tpc * 20 + tgc] + emb[t * 20 + tgc];
    }
  }
#pragma unroll
  for (int o = 32; o > 0; o >>= 1) {
    part += __shfl_xor(part, o);
    cntm += __shfl_xor(cntm, o);
  }
  if (lane == 0) {
    int t0c = min(max(lab[0], 0), 19);
    float score = startt[t0c] + emb[t0c] + part;
    int last = max(cntm - 1, 0);
    int tlc = min(max(lab[last], 0), 19);
    score += endt[tlc];
    float llh = score - logZ;
    atomicAdd(out, llh * (-1.f / 64.f));
  }
}

// ---------------------------------------------------------------------------
extern "C" void kernel_launch(void* const* d_in, const int* in_sizes, int n_in,
                              void* d_out, int out_size, void* d_ws, size_t ws_size,
                              hipStream_t stream) {
  const float* x      = (const float*)d_in[0];
  const int* labels   = (const int*)d_in[1];
  const float* Wih0   = (const float*)d_in[3];
  const float* Whh0   = (const float*)d_in[4];
  const float* bih0   = (const float*)d_in[5];
  const float* bhh0   = (const float*)d_in[6];
  const float* Wih1   = (const float*)d_in[7];
  const float* Whh1   = (const float*)d_in[8];
  const float* bih1   = (const float*)d_in[9];
  const float* bhh1   = (const float*)d_in[10];
  const float* fcw    = (const float*)d_in[11];
  const float* fcb    = (const float*)d_in[12];
  const float* startt = (const float*)d_in[13];
  const float* endt   = (const float*)d_in[14];
  const float* trans  = (const float*)d_in[15];
  float* out = (float*)d_out;

  char* ws = (char*)d_ws;
  size_t off = 0;
  auto alloc = [&](size_t bytes) -> void* {
    void* p = ws + off;
    off = (off + bytes + 255) & ~(size_t)255;
    return p;
  };
  unsigned short* h1_all = (unsigned short*)alloc(33554432ull * 2);  // 64 MB
  unsigned short* WH0f   = (unsigned short*)alloc(4194304ull * 2);   // 8 MB
  unsigned short* WI0f   = (unsigned short*)alloc(2097152ull * 2);   // 4 MB
  unsigned short* WH1f   = (unsigned short*)alloc(4194304ull * 2);   // 8 MB
  unsigned short* WI1f   = (unsigned short*)alloc(4194304ull * 2);   // 8 MB
  unsigned short* fcw_b  = (unsigned short*)alloc(20480ull * 2);
  float* bias0           = (float*)alloc(4096 * 4);
  float* bias1           = (float*)alloc(4096 * 4);
  unsigned short* h0r    = (unsigned short*)alloc(262144ull * 2);  // 4 slabs
  unsigned short* h1r    = (unsigned short*)alloc(262144ull * 2);
  float* em              = (float*)alloc(32768ull * 20 * 4);
  unsigned* flags        = (unsigned*)alloc(2048);

  if (off > ws_size) {
    unsigned wsmb = (unsigned)(ws_size >> 20);
    fallback_k<<<1, 1, 0, stream>>>(out, wsmb);
    return;
  }

  // Optional bf16 copy of x (32 MB)
  unsigned short* x_b = nullptr;
  if (off + 33554432ull + 512 <= ws_size) {
    x_b = (unsigned short*)alloc(16777216ull * 2);
  }

  hipMemsetAsync(flags, 0, 2048, stream);
  hipMemsetAsync(d_out, 0, sizeof(float), stream);

  // One-time weight repacks (fp32 -> fragment-linear bf16 streams).
  repack_w<<<2048, 256, 0, stream>>>(Whh0, WH0f, 1024, 5, 1);
  repack_w<<<1024, 256, 0, stream>>>(Wih0, WI0f, 512, 4, 0);
  repack_w<<<2048, 256, 0, stream>>>(Whh1, WH1f, 1024, 5, 1);
  repack_w<<<2048, 256, 0, stream>>>(Wih1, WI1f, 1024, 5, 1);
  perm_fcw<<<80, 256, 0, stream>>>(fcw, fcw_b);
  if (x_b) cvt_bf16<<<16384, 256, 0, stream>>>(x, x_b, 16777216);
  add_vec<<<16, 256, 0, stream>>>(bih0, bhh0, bias0, 4096);
  add_vec<<<16, 256, 0, stream>>>(bih1, bhh1, bias1, 4096);

  {
    void* args[] = {(void*)&x, (void*)&x_b, (void*)&WH0f, (void*)&WI0f,
                    (void*)&WH1f, (void*)&WI1f, (void*)&bias0, (void*)&bias1,
                    (void*)&h1_all, (void*)&h0r, (void*)&h1r, (void*)&flags};
    hipLaunchCooperativeKernel((void*)lstm_fused, dim3(64), dim3(256), args,
                               0, stream);
  }
  emis_k<<<512, 256, 0, stream>>>(h1_all, fcw_b, fcb, em);
  crf_k<<<16, 256, 0, stream>>>(em, labels, startt, endt, trans, out);
}

// Round 5
// 6994.515 us; speedup vs baseline: 10.9431x; 10.9431x over previous
//
#include <hip/hip_runtime.h>
#include <hip/hip_bf16.h>
#include <stdint.h>

// ---------------------------------------------------------------------------
// 2-layer LSTM + linear + CRF NLL on MI355X.
// Round 13: "rename, don't invalidate". R12 proved weights must be LDS-
// resident (L2-streaming refetched 45MB/step from fabric = 131us/step) and
// that FETCH counts L2 fills. R9-R11's invariant 19.5us/step at 48MB/step of
// IC-sourced h reads = ~2.5TB/s IC ceiling; R9's cached-read fix failed only
// because its per-step buffer_inv wiped L2 (reads stayed IC-sourced).
// Fix: write-once h arrays (h0_all/h1_all [64][512][1024]) -> no address is
// ever rewritten -> consumer plain cached loads are coherent with NO
// invalidation (first touch is post-flag; dispatch boundaries invalidate
// across bench iterations). Per-XCD L2 absorbs the 16-block broadcast:
// unique fabric traffic 48 -> ~3 MB/step. Also: purely forward dep graph
// (L0 never waits on L1; no slab reuse), h1 ring store == h1_all store.
// Keep R8 LDS weights, R10 split waits + x-before-wait + packed stores,
// natural layouts (R12's permuted-k absmax=16 reverted).
// ---------------------------------------------------------------------------

typedef __bf16 bf16x8 __attribute__((ext_vector_type(8)));
typedef float f32x4 __attribute__((ext_vector_type(4)));
typedef unsigned u32x4 __attribute__((ext_vector_type(4)));

__device__ __forceinline__ f32x4 mfma16(bf16x8 a, bf16x8 b, f32x4 c) {
  return __builtin_amdgcn_mfma_f32_16x16x32_bf16(a, b, c, 0, 0, 0);
}

__device__ __forceinline__ unsigned short f2bf(float f) {
  unsigned u = __float_as_uint(f);
  u = u + 0x7fffu + ((u >> 16) & 1u);
  return (unsigned short)(u >> 16);
}
__device__ __forceinline__ float sigf(float x) { return 1.f / (1.f + __expf(-x)); }
__device__ __forceinline__ float tanh_s(float x) {
  float a = fabsf(x);
  float e = __expf(2.f * a);
  float r = 1.f - 2.f / (e + 1.f);
  return copysignf(r, x);
}
__device__ __forceinline__ bf16x8 cvt8(const float* p) {
  float4 a = *(const float4*)p;
  float4 b = *(const float4*)(p + 4);
  union { bf16x8 v; unsigned short u[8]; } r;
  r.u[0] = f2bf(a.x); r.u[1] = f2bf(a.y); r.u[2] = f2bf(a.z); r.u[3] = f2bf(a.w);
  r.u[4] = f2bf(b.x); r.u[5] = f2bf(b.y); r.u[6] = f2bf(b.z); r.u[7] = f2bf(b.w);
  return r.v;
}

// ---- agent-scope (IC-coherent) primitives: flags + h write-through ----
__device__ __forceinline__ unsigned ald32(const unsigned* p) {
  return __hip_atomic_load(p, __ATOMIC_RELAXED, __HIP_MEMORY_SCOPE_AGENT);
}
__device__ __forceinline__ void ast32(void* p, unsigned v) {
  __hip_atomic_store((unsigned*)p, v, __ATOMIC_RELAXED, __HIP_MEMORY_SCOPE_AGENT);
}
__device__ __forceinline__ void st16_sc1(void* p, u32x4 v) {
  asm volatile("global_store_dwordx4 %0, %1, off sc1" :: "v"(p), "v"(v) : "memory");
}

__device__ __forceinline__ unsigned wave_min(unsigned v) {
#pragma unroll
  for (int o = 32; o > 0; o >>= 1) {
    unsigned t = (unsigned)__shfl_xor((int)v, o);
    v = t < v ? t : v;
  }
  return v;
}

// ---------------------------------------------------------------------------
__global__ void fallback_k(float* out, unsigned wsmb) { *out = -(float)wsmb; }

__global__ void cvt_bf16(const float* __restrict__ in, unsigned short* __restrict__ out, int n) {
  int i = (blockIdx.x * 256 + threadIdx.x) * 4;
  if (i < n) {
    float4 v = *(const float4*)(in + i);
    ushort4 o;
    o.x = f2bf(v.x); o.y = f2bf(v.y); o.z = f2bf(v.z); o.w = f2bf(v.w);
    *(ushort4*)(out + i) = o;
  }
}

__global__ void add_vec(const float* __restrict__ a, const float* __restrict__ b,
                        float* __restrict__ o, int n) {
  int i = blockIdx.x * 256 + threadIdx.x;
  if (i < n) o[i] = a[i] + b[i];
}

// ---------------------------------------------------------------------------
// Fused 2-layer persistent scan. 128 blocks/layer x 8 cols, weights in LDS
// (R8 scheme). h storage is WRITE-ONCE: h0_all/h1_all [64 b][512 s][1024 j]
// bf16. Producers store sc1 (write-through to IC, bypassing own L2);
// consumers use PLAIN CACHED loads - safe because each address is written
// exactly once and first touched after the producer's flag.
// Flags (monotonic): 1 = staged, s+2 = step s done (data in IC).
// Waits: L0 s: own>=s+1 only (NO cross-layer wait - no slab reuse).
//        L1 s: own>=s+1, then other>=s+2.
#define BS(mi, ks)  (*(const bf16x8*)&Bsm[(((mi)*2048 + (ks)*64 + lane)) * 8])
#define WS0(mi, ks) (*(const bf16x8*)&Bsm[32768 + (((mi)*1024 + (ks)*64 + lane)) * 8])
#define WS1(mi, ks) (*(const bf16x8*)&Bsm[32768 + (((mi)*2048 + (ks)*64 + lane)) * 8])

__global__ __launch_bounds__(256, 1) void lstm_fused(
    const float* __restrict__ x,              // [64][512][512] fp32 (fallback)
    const unsigned short* __restrict__ xb,    // [64][512][512] bf16 (or null)
    const unsigned short* __restrict__ Whh0b, const unsigned short* __restrict__ Wih0b,
    const unsigned short* __restrict__ Whh1b, const unsigned short* __restrict__ Wih1b,
    const float* __restrict__ bias0, const float* __restrict__ bias1,
    unsigned short* __restrict__ h1_all,      // [64][512][1024] bf16 (write-once)
    unsigned short* __restrict__ h0_all,      // [64][512][1024] bf16 (write-once)
    unsigned* flags)   // [0..127]=L0 arrivals, [128..255]=L1 arrivals
{
  extern __shared__ __align__(16) unsigned short Bsm[];
  const int tid = threadIdx.x;
  const int lane = tid & 63;
  const int w = tid >> 6;            // wave = 16-batch tile
  const int c16 = lane & 15, rg = lane >> 4;
  const bool is1 = blockIdx.x >= 128;
  const int bid = is1 ? (int)blockIdx.x - 128 : (int)blockIdx.x;
  const int j0 = bid * 8;
  unsigned* fown = flags + (is1 ? 128 : 0);
  unsigned* foth = flags + (is1 ? 0 : 128);

  // ---- LDS: Whh A-frags. unit u = mi*2048 + ks*64 + ln; ln is the MFMA lane:
  // m=ln&15 -> (gate=m&3, jj=m>>2); k = ks*32 + (ln>>4)*8.
  {
    const unsigned short* W = is1 ? Whh1b : Whh0b;
    for (int u = tid; u < 4096; u += 256) {
      int mi = u >> 11;
      int ks = (u >> 6) & 31;
      int ln = u & 63;
      int m = ln & 15;
      long row = (long)(m & 3) * 1024 + j0 + mi * 4 + (m >> 2);
      *(bf16x8*)&Bsm[u * 8] = *(const bf16x8*)(W + row * 1024 + ks * 32 + (ln >> 4) * 8);
    }
  }
  // ---- LDS: Wih A-frags (K=512 for L0, K=1024 for L1) ----
  if (is1) {
    for (int u = tid; u < 4096; u += 256) {
      int mi = u >> 11;
      int ks = (u >> 6) & 31;
      int ln = u & 63;
      int m = ln & 15;
      long row = (long)(m & 3) * 1024 + j0 + mi * 4 + (m >> 2);
      *(bf16x8*)&Bsm[32768 + u * 8] =
          *(const bf16x8*)(Wih1b + row * 1024 + ks * 32 + (ln >> 4) * 8);
    }
  } else {
    for (int u = tid; u < 2048; u += 256) {
      int mi = u >> 10;
      int ks = (u >> 6) & 15;
      int ln = u & 63;
      int m = ln & 15;
      long row = (long)(m & 3) * 1024 + j0 + mi * 4 + (m >> 2);
      *(bf16x8*)&Bsm[32768 + u * 8] =
          *(const bf16x8*)(Wih0b + row * 512 + ks * 32 + (ln >> 4) * 8);
    }
  }
  // ---- biases ----
  const float* bias = is1 ? bias1 : bias0;
  float bs[2][4];
#pragma unroll
  for (int mi = 0; mi < 2; ++mi)
#pragma unroll
    for (int r = 0; r < 4; ++r) bs[mi][r] = bias[r * 1024 + j0 + mi * 4 + rg];

  __syncthreads();                       // LDS staged
  if (tid == 0) ast32(fown + bid, 1u);   // staged arrival

  const int b = w * 16 + c16;
  const int ko = rg * 8;
  float cst[2] = {0.f, 0.f};
  const f32x4 fz = {0.f, 0.f, 0.f, 0.f};

  if (!is1) {
    // ================= layer 0 =================
    for (int s = 0; s < 512; ++s) {
      // ---- x-part MFMA: no cross-block dependency, before the wait ----
      f32x4 aI0 = fz, aI1 = fz;
      if (xb) {
        const unsigned short* xp = xb + ((long)b * 512 + s) * 512 + ko;
#pragma unroll
        for (int ks = 0; ks < 16; ++ks) {
          bf16x8 xv = *(const bf16x8*)(xp + ks * 32);
          aI0 = mfma16(WS0(0, ks), xv, aI0);
          aI1 = mfma16(WS0(1, ks), xv, aI1);
        }
      } else {
        const float* xp = x + ((long)b * 512 + s) * 512 + ko;
#pragma unroll
        for (int ks = 0; ks < 16; ++ks) {
          bf16x8 xv = cvt8(xp + ks * 32);
          aI0 = mfma16(WS0(0, ks), xv, aI0);
          aI1 = mfma16(WS0(1, ks), xv, aI1);
        }
      }
      // ---- wait: own layer finished step s-1 (wave 0 polls) ----
      const unsigned t_own = (unsigned)(s + 1);
      if (w == 0) {
        for (;;) {
          unsigned a = ald32(fown + lane);
          unsigned b2 = ald32(fown + lane + 64);
          if (wave_min(a < b2 ? a : b2) >= t_own) break;
          __builtin_amdgcn_s_sleep(1);
        }
      }
      __syncthreads();
      __atomic_signal_fence(__ATOMIC_ACQ_REL);

      // ---- h-part: plain cached reads of write-once h0[s-1] ----
      f32x4 aW0 = fz, aW1 = fz;
      if (s > 0) {
        const unsigned short* hp = h0_all + ((long)b * 512 + (s - 1)) * 1024 + ko;
        bf16x8 hfr[32];
#pragma unroll
        for (int ks = 0; ks < 32; ++ks) hfr[ks] = *(const bf16x8*)(hp + ks * 32);
        __builtin_amdgcn_sched_barrier(0);
#pragma unroll
        for (int ks = 0; ks < 32; ++ks) {
          aW0 = mfma16(BS(0, ks), hfr[ks], aW0);
          aW1 = mfma16(BS(1, ks), hfr[ks], aW1);
        }
      }
      // ---- gates, packed 16B sc1 store ----
      unsigned huv[2];
#pragma unroll
      for (int mi = 0; mi < 2; ++mi) {
        float p_i = (mi ? aW1[0] + aI1[0] : aW0[0] + aI0[0]) + bs[mi][0];
        float p_f = (mi ? aW1[1] + aI1[1] : aW0[1] + aI0[1]) + bs[mi][1];
        float p_g = (mi ? aW1[2] + aI1[2] : aW0[2] + aI0[2]) + bs[mi][2];
        float p_o = (mi ? aW1[3] + aI1[3] : aW0[3] + aI0[3]) + bs[mi][3];
        float iv = sigf(p_i);
        float fv = sigf(p_f);
        float gv = tanh_s(p_g);
        float ov = sigf(p_o);
        float cn = fv * cst[mi] + iv * gv;
        cst[mi] = cn;
        huv[mi] = (unsigned)f2bf(ov * tanh_s(cn));
      }
      unsigned p0 = (unsigned)__shfl_xor((int)huv[0], 16);
      unsigned p1 = (unsigned)__shfl_xor((int)huv[1], 16);
      unsigned w0 = huv[0] | (p0 << 16);   // rg even: cols (j0+mi*4+rg, +1)
      unsigned w1 = huv[1] | (p1 << 16);
      unsigned q0 = (unsigned)__shfl_xor((int)w0, 32);
      unsigned q1 = (unsigned)__shfl_xor((int)w1, 32);
      if (rg == 0) {
        u32x4 v = {w0, q0, w1, q1};        // cols j0..j0+7
        st16_sc1(h0_all + ((long)b * 512 + s) * 1024 + j0, v);
      }
      asm volatile("s_waitcnt vmcnt(0)" ::: "memory");
      __syncthreads();
      if (tid == 0) ast32(fown + bid, (unsigned)(s + 2));
    }
  } else {
    // ================= layer 1 =================
    for (int s = 0; s < 512; ++s) {
      // ---- wait A: own layer finished s-1 ----
      const unsigned t_own = (unsigned)(s + 1);
      if (w == 0) {
        for (;;) {
          unsigned a = ald32(fown + lane);
          unsigned b2 = ald32(fown + lane + 64);
          if (wave_min(a < b2 ? a : b2) >= t_own) break;
          __builtin_amdgcn_s_sleep(1);
        }
      }
      __syncthreads();
      __atomic_signal_fence(__ATOMIC_ACQ_REL);

      f32x4 aW0 = fz, aW1 = fz;
      if (s > 0) {
        const unsigned short* hp = h1_all + ((long)b * 512 + (s - 1)) * 1024 + ko;
        bf16x8 hfr[32];
#pragma unroll
        for (int ks = 0; ks < 32; ++ks) hfr[ks] = *(const bf16x8*)(hp + ks * 32);
        __builtin_amdgcn_sched_barrier(0);
#pragma unroll
        for (int ks = 0; ks < 32; ++ks) {
          aW0 = mfma16(BS(0, ks), hfr[ks], aW0);
          aW1 = mfma16(BS(1, ks), hfr[ks], aW1);
        }
      }
      // ---- wait B: L0 finished step s (Whh1 compute overlapped above) ----
      const unsigned t_oth = (unsigned)(s + 2);
      if (w == 0) {
        for (;;) {
          unsigned a = ald32(foth + lane);
          unsigned b2 = ald32(foth + lane + 64);
          if (wave_min(a < b2 ? a : b2) >= t_oth) break;
          __builtin_amdgcn_s_sleep(1);
        }
      }
      __syncthreads();
      __atomic_signal_fence(__ATOMIC_ACQ_REL);

      f32x4 aI0 = fz, aI1 = fz;
      {
        const unsigned short* hp = h0_all + ((long)b * 512 + s) * 1024 + ko;
        bf16x8 hfr[32];
#pragma unroll
        for (int ks = 0; ks < 32; ++ks) hfr[ks] = *(const bf16x8*)(hp + ks * 32);
        __builtin_amdgcn_sched_barrier(0);
#pragma unroll
        for (int ks = 0; ks < 32; ++ks) {
          aI0 = mfma16(WS1(0, ks), hfr[ks], aI0);
          aI1 = mfma16(WS1(1, ks), hfr[ks], aI1);
        }
      }
      // ---- gates, packed 16B sc1 store (serves ring AND output) ----
      unsigned huv[2];
#pragma unroll
      for (int mi = 0; mi < 2; ++mi) {
        float p_i = (mi ? aW1[0] + aI1[0] : aW0[0] + aI0[0]) + bs[mi][0];
        float p_f = (mi ? aW1[1] + aI1[1] : aW0[1] + aI0[1]) + bs[mi][1];
        float p_g = (mi ? aW1[2] + aI1[2] : aW0[2] + aI0[2]) + bs[mi][2];
        float p_o = (mi ? aW1[3] + aI1[3] : aW0[3] + aI0[3]) + bs[mi][3];
        float iv = sigf(p_i);
        float fv = sigf(p_f);
        float gv = tanh_s(p_g);
        float ov = sigf(p_o);
        float cn = fv * cst[mi] + iv * gv;
        cst[mi] = cn;
        huv[mi] = (unsigned)f2bf(ov * tanh_s(cn));
      }
      unsigned p0 = (unsigned)__shfl_xor((int)huv[0], 16);
      unsigned p1 = (unsigned)__shfl_xor((int)huv[1], 16);
      unsigned w0 = huv[0] | (p0 << 16);
      unsigned w1 = huv[1] | (p1 << 16);
      unsigned q0 = (unsigned)__shfl_xor((int)w0, 32);
      unsigned q1 = (unsigned)__shfl_xor((int)w1, 32);
      if (rg == 0) {
        u32x4 v = {w0, q0, w1, q1};
        st16_sc1(h1_all + ((long)b * 512 + s) * 1024 + j0, v);
      }
      asm volatile("s_waitcnt vmcnt(0)" ::: "memory");
      __syncthreads();
      if (tid == 0) ast32(fown + bid, (unsigned)(s + 2));
    }
  }
}

// ---------------------------------------------------------------------------
// emissions[m][c] = h1[m][:] . fc_w[c][:] + fc_b[c], c<20 (N padded to 32).
__global__ __launch_bounds__(256) void emis_k(
    const unsigned short* __restrict__ h1, const unsigned short* __restrict__ fcw,
    const float* __restrict__ fcb, float* __restrict__ em) {
  __shared__ __align__(16) unsigned short Bsm[32768];
  const int tid = threadIdx.x;
  const int lane = tid & 63;
  const int w = tid >> 6;
  const int c16 = lane & 15, rg = lane >> 4;
  for (int u = tid; u < 4096; u += 256) {
    int tile = u >> 11;
    int ks = (u >> 6) & 31;
    int ln = u & 63;
    int n = tile * 16 + (ln & 15);
    int kb = ks * 32 + (ln >> 4) * 8;
    if (n < 20) {
      *(bf16x8*)&Bsm[u * 8] = *(const bf16x8*)(fcw + (long)n * 1024 + kb);
    } else {
#pragma unroll
      for (int j = 0; j < 8; ++j) Bsm[u * 8 + j] = 0;
    }
  }
  __syncthreads();
  const long r0 = (long)blockIdx.x * 64;
  const bf16x8* arow = (const bf16x8*)(h1 + (r0 + w * 16 + c16) * 1024 + rg * 8);
  const f32x4 fz = {0.f, 0.f, 0.f, 0.f};
  f32x4 acc0 = fz, acc1 = fz;
#pragma unroll 4
  for (int ks = 0; ks < 32; ++ks) {
    bf16x8 a = arow[ks * 4];
    acc0 = mfma16(a, *(const bf16x8*)&Bsm[(ks * 64 + lane) * 8], acc0);
    acc1 = mfma16(a, *(const bf16x8*)&Bsm[((32 + ks) * 64 + lane) * 8], acc1);
  }
#pragma unroll
  for (int r = 0; r < 4; ++r) {
    long row = r0 + w * 16 + rg * 4 + r;
    em[row * 20 + c16] = acc0[r] + fcb[c16];
    int col1 = 16 + c16;
    if (col1 < 20) em[row * 20 + col1] = acc1[r] + fcb[col1];
  }
}

// ---------------------------------------------------------------------------
// CRF NLL: one wave per batch. Lanes 0..19 hold alpha[j]; 511 serial steps.
__global__ __launch_bounds__(256) void crf_k(
    const float* __restrict__ em, const int* __restrict__ labels,
    const float* __restrict__ startt, const float* __restrict__ endt,
    const float* __restrict__ trans, float* __restrict__ out) {
  const int lane = threadIdx.x & 63;
  const int b = blockIdx.x * 4 + (threadIdx.x >> 6);
  const float NEG = -1e30f;
  const int j = lane;
  const bool act = j < 20;
  float treg[20];
#pragma unroll
  for (int i = 0; i < 20; ++i) treg[i] = act ? trans[i * 20 + j] : 0.f;
  const float* emb = em + (long)b * 512 * 20;
  const int* lab = labels + (long)b * 512;
  float alpha = act ? (startt[j] + emb[j]) : NEG;
  for (int t = 1; t < 512; ++t) {
    float mx = NEG;
#pragma unroll
    for (int i = 0; i < 20; ++i) {
      float v = __shfl(alpha, i) + treg[i];
      mx = fmaxf(mx, v);
    }
    float s = 0.f;
#pragma unroll
    for (int i = 0; i < 20; ++i) {
      float v = __shfl(alpha, i) + treg[i];
      s += __expf(v - mx);
    }
    bool m = lab[t] != -1;
    float na = emb[t * 20 + (act ? j : 0)] + mx + __logf(s);
    if (act && m) alpha = na;
  }
  float v = act ? (alpha + endt[j]) : NEG;
  float mx = v;
#pragma unroll
  for (int o = 32; o > 0; o >>= 1) mx = fmaxf(mx, __shfl_xor(mx, o));
  float s = act ? __expf(v - mx) : 0.f;
#pragma unroll
  for (int o = 32; o > 0; o >>= 1) s += __shfl_xor(s, o);
  float logZ = mx + __logf(s);
  float part = 0.f;
  int cntm = 0;
  for (int t = lane; t < 512; t += 64) cntm += (lab[t] != -1) ? 1 : 0;
  for (int t = 1 + lane; t < 512; t += 64) {
    int tg = lab[t];
    if (tg != -1) {
      int tp = lab[t - 1];
      int tgc = min(max(tg, 0), 19);
      int tpc = min(max(tp, 0), 19);
      part += trans[tpc * 20 + tgc] + emb[t * 20 + tgc];
    }
  }
#pragma unroll
  for (int o = 32; o > 0; o >>= 1) {
    part += __shfl_xor(part, o);
    cntm += __shfl_xor(cntm, o);
  }
  if (lane == 0) {
    int t0c = min(max(lab[0], 0), 19);
    float score = startt[t0c] + emb[t0c] + part;
    int last = max(cntm - 1, 0);
    int tlc = min(max(lab[last], 0), 19);
    score += endt[tlc];
    float llh = score - logZ;
    atomicAdd(out, llh * (-1.f / 64.f));
  }
}

// ---------------------------------------------------------------------------
extern "C" void kernel_launch(void* const* d_in, const int* in_sizes, int n_in,
                              void* d_out, int out_size, void* d_ws, size_t ws_size,
                              hipStream_t stream) {
  const float* x      = (const float*)d_in[0];
  const int* labels   = (const int*)d_in[1];
  const float* Wih0   = (const float*)d_in[3];
  const float* Whh0   = (const float*)d_in[4];
  const float* bih0   = (const float*)d_in[5];
  const float* bhh0   = (const float*)d_in[6];
  const float* Wih1   = (const float*)d_in[7];
  const float* Whh1   = (const float*)d_in[8];
  const float* bih1   = (const float*)d_in[9];
  const float* bhh1   = (const float*)d_in[10];
  const float* fcw    = (const float*)d_in[11];
  const float* fcb    = (const float*)d_in[12];
  const float* startt = (const float*)d_in[13];
  const float* endt   = (const float*)d_in[14];
  const float* trans  = (const float*)d_in[15];
  float* out = (float*)d_out;

  char* ws = (char*)d_ws;
  size_t off = 0;
  auto alloc = [&](size_t bytes) -> void* {
    void* p = ws + off;
    off = (off + bytes + 255) & ~(size_t)255;
    return p;
  };
  unsigned short* h1_all = (unsigned short*)alloc(33554432ull * 2);  // 64 MB
  unsigned short* h0_all = (unsigned short*)alloc(33554432ull * 2);  // 64 MB
  unsigned short* Whh0_b = (unsigned short*)alloc(4194304ull * 2);
  unsigned short* Wih0_b = (unsigned short*)alloc(2097152ull * 2);
  unsigned short* Whh1_b = (unsigned short*)alloc(4194304ull * 2);
  unsigned short* Wih1_b = (unsigned short*)alloc(4194304ull * 2);
  unsigned short* fcw_b  = (unsigned short*)alloc(20480ull * 2);
  float* bias0           = (float*)alloc(4096 * 4);
  float* bias1           = (float*)alloc(4096 * 4);
  float* em              = (float*)alloc(32768ull * 20 * 4);
  unsigned* flags        = (unsigned*)alloc(2048);

  if (off > ws_size) {
    unsigned wsmb = (unsigned)(ws_size >> 20);
    fallback_k<<<1, 1, 0, stream>>>(out, wsmb);
    return;
  }

  // Optional bf16 copy of x (32 MB)
  unsigned short* x_b = nullptr;
  if (off + 33554432ull + 512 <= ws_size) {
    x_b = (unsigned short*)alloc(16777216ull * 2);
  }

  hipMemsetAsync(flags, 0, 2048, stream);
  hipMemsetAsync(d_out, 0, sizeof(float), stream);

  cvt_bf16<<<4096, 256, 0, stream>>>(Whh0, Whh0_b, 4194304);
  cvt_bf16<<<2048, 256, 0, stream>>>(Wih0, Wih0_b, 2097152);
  cvt_bf16<<<4096, 256, 0, stream>>>(Whh1, Whh1_b, 4194304);
  cvt_bf16<<<4096, 256, 0, stream>>>(Wih1, Wih1_b, 4194304);
  cvt_bf16<<<20, 256, 0, stream>>>(fcw, fcw_b, 20480);
  if (x_b) cvt_bf16<<<16384, 256, 0, stream>>>(x, x_b, 16777216);
  add_vec<<<16, 256, 0, stream>>>(bih0, bhh0, bias0, 4096);
  add_vec<<<16, 256, 0, stream>>>(bih1, bhh1, bias1, 4096);

  {
    static bool attr_set = false;   // host-side only; same work every call
    if (!attr_set) {
      hipFuncSetAttribute((const void*)lstm_fused,
                          hipFuncAttributeMaxDynamicSharedMemorySize, 131072);
      attr_set = true;
    }
    void* args[] = {(void*)&x, (void*)&x_b, (void*)&Whh0_b, (void*)&Wih0_b,
                    (void*)&Whh1_b, (void*)&Wih1_b, (void*)&bias0, (void*)&bias1,
                    (void*)&h1_all, (void*)&h0_all, (void*)&flags};
    hipLaunchCooperativeKernel((void*)lstm_fused, dim3(256), dim3(256), args,
                               131072, stream);
  }
  emis_k<<<512, 256, 0, stream>>>(h1_all, fcw_b, fcb, em);
  crf_k<<<16, 256, 0, stream>>>(em, labels, startt, endt, trans, out);
}

// Round 6
// 3339.332 us; speedup vs baseline: 22.9213x; 2.0946x over previous
//
#include <hip/hip_runtime.h>
#include <hip/hip_bf16.h>
#include <stdint.h>

// ---------------------------------------------------------------------------
// 2-layer LSTM + linear + CRF NLL on MI355X.
// Round 14 (on R13's -34% win):
//  1. CHUNK LAYOUT for h rings: h[s][chunk c=col/8][batch][8 cols] -> each
//     block's per-step output is 1KB CONTIGUOUS (16 full 64B lines) instead
//     of 64 scattered 16B partial-line write-through stores 1MB apart.
//     Consumer reads stay coalesced (chunk c = ks*4+rg). Write-once renaming
//     preserved (full 512-deep arrays).
//  2. L1 reorder: waitB(L0)+h0-part FIRST, then waitA(own)+h1-part. L0 runs
//     ahead (no back-pressure), so waitB ~free and L1's serial chain becomes
//     symmetric with L0's.
//  3. emis_k remapped (block = one timestep, all 64 batches) so it reads the
//     chunk layout fully coalesced; h1_all duplicate eliminated (-64MB ws).
//  4. Instrumentation: L1 total wait ticks -> WRITE_SIZE (+1B/tick, proven
//     exact channel); L0 own-wait ticks -> SQ_LDS_BANK_CONFLICT (baseline
//     0.0; one 64-lane same-bank ds_read per 8 ticks ~= ~25 counts each).
// ---------------------------------------------------------------------------

typedef __bf16 bf16x8 __attribute__((ext_vector_type(8)));
typedef float f32x4 __attribute__((ext_vector_type(4)));
typedef unsigned u32x4 __attribute__((ext_vector_type(4)));

__device__ __forceinline__ f32x4 mfma16(bf16x8 a, bf16x8 b, f32x4 c) {
  return __builtin_amdgcn_mfma_f32_16x16x32_bf16(a, b, c, 0, 0, 0);
}

__device__ __forceinline__ unsigned short f2bf(float f) {
  unsigned u = __float_as_uint(f);
  u = u + 0x7fffu + ((u >> 16) & 1u);
  return (unsigned short)(u >> 16);
}
__device__ __forceinline__ float sigf(float x) { return 1.f / (1.f + __expf(-x)); }
__device__ __forceinline__ float tanh_s(float x) {
  float a = fabsf(x);
  float e = __expf(2.f * a);
  float r = 1.f - 2.f / (e + 1.f);
  return copysignf(r, x);
}
__device__ __forceinline__ bf16x8 cvt8(const float* p) {
  float4 a = *(const float4*)p;
  float4 b = *(const float4*)(p + 4);
  union { bf16x8 v; unsigned short u[8]; } r;
  r.u[0] = f2bf(a.x); r.u[1] = f2bf(a.y); r.u[2] = f2bf(a.z); r.u[3] = f2bf(a.w);
  r.u[4] = f2bf(b.x); r.u[5] = f2bf(b.y); r.u[6] = f2bf(b.z); r.u[7] = f2bf(b.w);
  return r.v;
}

// ---- agent-scope (IC-coherent) primitives: flags + h write-through ----
__device__ __forceinline__ unsigned ald32(const unsigned* p) {
  return __hip_atomic_load(p, __ATOMIC_RELAXED, __HIP_MEMORY_SCOPE_AGENT);
}
__device__ __forceinline__ unsigned long long ald64(const void* p) {
  return __hip_atomic_load((const unsigned long long*)p, __ATOMIC_RELAXED,
                           __HIP_MEMORY_SCOPE_AGENT);
}
__device__ __forceinline__ void ast32(void* p, unsigned v) {
  __hip_atomic_store((unsigned*)p, v, __ATOMIC_RELAXED, __HIP_MEMORY_SCOPE_AGENT);
}
__device__ __forceinline__ void st16_sc1(void* p, u32x4 v) {
  asm volatile("global_store_dwordx4 %0, %1, off sc1" :: "v"(p), "v"(v) : "memory");
}

__device__ __forceinline__ unsigned wave_min(unsigned v) {
#pragma unroll
  for (int o = 32; o > 0; o >>= 1) {
    unsigned t = (unsigned)__shfl_xor((int)v, o);
    v = t < v ? t : v;
  }
  return v;
}

// ---------------------------------------------------------------------------
__global__ void fallback_k(float* out, unsigned wsmb) { *out = -(float)wsmb; }

__global__ void cvt_bf16(const float* __restrict__ in, unsigned short* __restrict__ out, int n) {
  int i = (blockIdx.x * 256 + threadIdx.x) * 4;
  if (i < n) {
    float4 v = *(const float4*)(in + i);
    ushort4 o;
    o.x = f2bf(v.x); o.y = f2bf(v.y); o.z = f2bf(v.z); o.w = f2bf(v.w);
    *(ushort4*)(out + i) = o;
  }
}

__global__ void add_vec(const float* __restrict__ a, const float* __restrict__ b,
                        float* __restrict__ o, int n) {
  int i = blockIdx.x * 256 + threadIdx.x;
  if (i < n) o[i] = a[i] + b[i];
}

// ---------------------------------------------------------------------------
// Chunk layout: h[s][c][b][e] at ushort offset s*65536 + c*512 + b*8 + e,
// where c = col/8 (0..127), e = col%8. Write-once over the whole kernel.
// Flags (monotonic): 1 = LDS staged, s+2 = step s data in IC.
// Waits: L0 s: own>=s+1. L1 s: other>=s+2 (h0[s]), then own>=s+1 (h1[s-1]).
#define BS(mi, ks)  (*(const bf16x8*)&Bsm[(((mi)*2048 + (ks)*64 + lane)) * 8])
#define WS0(mi, ks) (*(const bf16x8*)&Bsm[32768 + (((mi)*1024 + (ks)*64 + lane)) * 8])
#define WS1(mi, ks) (*(const bf16x8*)&Bsm[32768 + (((mi)*2048 + (ks)*64 + lane)) * 8])

__global__ __launch_bounds__(256, 1) void lstm_fused(
    const float* __restrict__ x,              // [64][512][512] fp32 (fallback)
    const unsigned short* __restrict__ xb,    // [64][512][512] bf16 (or null)
    const unsigned short* __restrict__ Whh0b, const unsigned short* __restrict__ Wih0b,
    const unsigned short* __restrict__ Whh1b, const unsigned short* __restrict__ Wih1b,
    const float* __restrict__ bias0, const float* __restrict__ bias1,
    unsigned short* __restrict__ h0r,         // [512][128][64][8] write-once
    unsigned short* __restrict__ h1r,         // [512][128][64][8] write-once
    unsigned* flags,   // [0..127]=L0 arrivals, [128..255]=L1 arrivals
    unsigned* instr)   // WRITE-channel scratch
{
  extern __shared__ __align__(16) unsigned short Bsm[];
  const int tid = threadIdx.x;
  const int lane = tid & 63;
  const int w = tid >> 6;            // wave = 16-batch tile
  const int c16 = lane & 15, rg = lane >> 4;
  const bool is1 = blockIdx.x >= 128;
  const int bid = is1 ? (int)blockIdx.x - 128 : (int)blockIdx.x;
  const int j0 = bid * 8;
  unsigned* fown = flags + (is1 ? 128 : 0);
  unsigned* foth = flags + (is1 ? 0 : 128);

  // ---- LDS: Whh A-frags (R8 scheme) ----
  {
    const unsigned short* W = is1 ? Whh1b : Whh0b;
    for (int u = tid; u < 4096; u += 256) {
      int mi = u >> 11;
      int ks = (u >> 6) & 31;
      int ln = u & 63;
      int m = ln & 15;
      long row = (long)(m & 3) * 1024 + j0 + mi * 4 + (m >> 2);
      *(bf16x8*)&Bsm[u * 8] = *(const bf16x8*)(W + row * 1024 + ks * 32 + (ln >> 4) * 8);
    }
  }
  // ---- LDS: Wih A-frags (K=512 for L0, K=1024 for L1) ----
  if (is1) {
    for (int u = tid; u < 4096; u += 256) {
      int mi = u >> 11;
      int ks = (u >> 6) & 31;
      int ln = u & 63;
      int m = ln & 15;
      long row = (long)(m & 3) * 1024 + j0 + mi * 4 + (m >> 2);
      *(bf16x8*)&Bsm[32768 + u * 8] =
          *(const bf16x8*)(Wih1b + row * 1024 + ks * 32 + (ln >> 4) * 8);
    }
  } else {
    for (int u = tid; u < 2048; u += 256) {
      int mi = u >> 10;
      int ks = (u >> 6) & 15;
      int ln = u & 63;
      int m = ln & 15;
      long row = (long)(m & 3) * 1024 + j0 + mi * 4 + (m >> 2);
      *(bf16x8*)&Bsm[32768 + u * 8] =
          *(const bf16x8*)(Wih0b + row * 512 + ks * 32 + (ln >> 4) * 8);
    }
  }
  // ---- biases ----
  const float* bias = is1 ? bias1 : bias0;
  float bs[2][4];
#pragma unroll
  for (int mi = 0; mi < 2; ++mi)
#pragma unroll
    for (int r = 0; r < 4; ++r) bs[mi][r] = bias[r * 1024 + j0 + mi * 4 + rg];

  __syncthreads();                       // LDS staged
  if (tid == 0) ast32(fown + bid, 1u);   // staged arrival

  const int b = w * 16 + c16;
  const int ko = rg * 8;
  float cst[2] = {0.f, 0.f};
  const f32x4 fz = {0.f, 0.f, 0.f, 0.f};
  unsigned long long wait_acc = 0;

  if (!is1) {
    // ================= layer 0 =================
    for (int s = 0; s < 512; ++s) {
      // ---- x-part MFMA: no cross-block dependency, before the wait ----
      f32x4 aI0 = fz, aI1 = fz;
      if (xb) {
        const unsigned short* xp = xb + ((long)b * 512 + s) * 512 + ko;
#pragma unroll
        for (int ks = 0; ks < 16; ++ks) {
          bf16x8 xv = *(const bf16x8*)(xp + ks * 32);
          aI0 = mfma16(WS0(0, ks), xv, aI0);
          aI1 = mfma16(WS0(1, ks), xv, aI1);
        }
      } else {
        const float* xp = x + ((long)b * 512 + s) * 512 + ko;
#pragma unroll
        for (int ks = 0; ks < 16; ++ks) {
          bf16x8 xv = cvt8(xp + ks * 32);
          aI0 = mfma16(WS0(0, ks), xv, aI0);
          aI1 = mfma16(WS0(1, ks), xv, aI1);
        }
      }
      // ---- wait: own layer finished step s-1 (wave 0 polls, timed) ----
      const unsigned t_own = (unsigned)(s + 1);
      if (w == 0) {
        unsigned long long t0 = __builtin_amdgcn_s_memrealtime();
        for (;;) {
          unsigned long long q = ald64(fown + 2 * lane);
          unsigned a = (unsigned)q, b2 = (unsigned)(q >> 32);
          if (wave_min(a < b2 ? a : b2) >= t_own) break;
          __builtin_amdgcn_s_sleep(1);
        }
        wait_acc += __builtin_amdgcn_s_memrealtime() - t0;
      }
      __syncthreads();
      __atomic_signal_fence(__ATOMIC_ACQ_REL);

      // ---- h-part: cached reads of write-once h0[s-1] (chunk layout) ----
      f32x4 aW0 = fz, aW1 = fz;
      if (s > 0) {
        const unsigned short* hp = h0r + (long)(s - 1) * 65536 + rg * 512 + b * 8;
        bf16x8 hfr[32];
#pragma unroll
        for (int ks = 0; ks < 32; ++ks) hfr[ks] = *(const bf16x8*)(hp + ks * 2048);
        __builtin_amdgcn_sched_barrier(0);
#pragma unroll
        for (int ks = 0; ks < 32; ++ks) {
          aW0 = mfma16(BS(0, ks), hfr[ks], aW0);
          aW1 = mfma16(BS(1, ks), hfr[ks], aW1);
        }
      }
      // ---- gates, pack, contiguous 16B sc1 store ----
      unsigned huv[2];
#pragma unroll
      for (int mi = 0; mi < 2; ++mi) {
        float p_i = (mi ? aW1[0] + aI1[0] : aW0[0] + aI0[0]) + bs[mi][0];
        float p_f = (mi ? aW1[1] + aI1[1] : aW0[1] + aI0[1]) + bs[mi][1];
        float p_g = (mi ? aW1[2] + aI1[2] : aW0[2] + aI0[2]) + bs[mi][2];
        float p_o = (mi ? aW1[3] + aI1[3] : aW0[3] + aI0[3]) + bs[mi][3];
        float iv = sigf(p_i);
        float fv = sigf(p_f);
        float gv = tanh_s(p_g);
        float ov = sigf(p_o);
        float cn = fv * cst[mi] + iv * gv;
        cst[mi] = cn;
        huv[mi] = (unsigned)f2bf(ov * tanh_s(cn));
      }
      unsigned p0 = (unsigned)__shfl_xor((int)huv[0], 16);
      unsigned p1 = (unsigned)__shfl_xor((int)huv[1], 16);
      unsigned w0 = huv[0] | (p0 << 16);
      unsigned w1 = huv[1] | (p1 << 16);
      unsigned q0 = (unsigned)__shfl_xor((int)w0, 32);
      unsigned q1 = (unsigned)__shfl_xor((int)w1, 32);
      if (rg == 0) {
        u32x4 v = {w0, q0, w1, q1};        // cols j0..j0+7, batch b
        st16_sc1(h0r + (long)s * 65536 + bid * 512 + b * 8, v);
      }
      asm volatile("s_waitcnt vmcnt(0)" ::: "memory");
      __syncthreads();
      if (tid == 0) ast32(fown + bid, (unsigned)(s + 2));
    }
    // ---- L0 wait export: SQ_LDS_BANK_CONFLICT channel (block 0 only) ----
    // one 64-lane same-bank ds_read per 8 ticks; ~25 counts per read.
    if (bid == 0 && w == 0) {
      unsigned long long n = wait_acc >> 3;
      if (n > (1ull << 19)) n = 1ull << 19;
      int addr = lane * 128;                 // all lanes -> bank 0
      for (unsigned long long i = 0; i < n; ++i) {
        float v;
        asm volatile("ds_read_b32 %0, %1" : "=v"(v) : "v"(addr));
        asm volatile("" :: "v"(v));
      }
      asm volatile("s_waitcnt lgkmcnt(0)" ::: "memory");
    }
  } else {
    // ================= layer 1 =================
    for (int s = 0; s < 512; ++s) {
      // ---- wait B FIRST: L0 finished step s (expected ~free, timed) ----
      const unsigned t_oth = (unsigned)(s + 2);
      if (w == 0) {
        unsigned long long t0 = __builtin_amdgcn_s_memrealtime();
        for (;;) {
          unsigned long long q = ald64(foth + 2 * lane);
          unsigned a = (unsigned)q, b2 = (unsigned)(q >> 32);
          if (wave_min(a < b2 ? a : b2) >= t_oth) break;
          __builtin_amdgcn_s_sleep(1);
        }
        wait_acc += __builtin_amdgcn_s_memrealtime() - t0;
      }
      __syncthreads();
      __atomic_signal_fence(__ATOMIC_ACQ_REL);

      // ---- h0-part (Wih1 . h0[s]) ----
      f32x4 aI0 = fz, aI1 = fz;
      {
        const unsigned short* hp = h0r + (long)s * 65536 + rg * 512 + b * 8;
        bf16x8 hfr[32];
#pragma unroll
        for (int ks = 0; ks < 32; ++ks) hfr[ks] = *(const bf16x8*)(hp + ks * 2048);
        __builtin_amdgcn_sched_barrier(0);
#pragma unroll
        for (int ks = 0; ks < 32; ++ks) {
          aI0 = mfma16(WS1(0, ks), hfr[ks], aI0);
          aI1 = mfma16(WS1(1, ks), hfr[ks], aI1);
        }
      }
      // ---- wait A: own layer finished s-1 (timed) ----
      const unsigned t_own = (unsigned)(s + 1);
      if (w == 0) {
        unsigned long long t0 = __builtin_amdgcn_s_memrealtime();
        for (;;) {
          unsigned long long q = ald64(fown + 2 * lane);
          unsigned a = (unsigned)q, b2 = (unsigned)(q >> 32);
          if (wave_min(a < b2 ? a : b2) >= t_own) break;
          __builtin_amdgcn_s_sleep(1);
        }
        wait_acc += __builtin_amdgcn_s_memrealtime() - t0;
      }
      __syncthreads();
      __atomic_signal_fence(__ATOMIC_ACQ_REL);

      // ---- h1-part (Whh1 . h1[s-1]) ----
      f32x4 aW0 = fz, aW1 = fz;
      if (s > 0) {
        const unsigned short* hp = h1r + (long)(s - 1) * 65536 + rg * 512 + b * 8;
        bf16x8 hfr[32];
#pragma unroll
        for (int ks = 0; ks < 32; ++ks) hfr[ks] = *(const bf16x8*)(hp + ks * 2048);
        __builtin_amdgcn_sched_barrier(0);
#pragma unroll
        for (int ks = 0; ks < 32; ++ks) {
          aW0 = mfma16(BS(0, ks), hfr[ks], aW0);
          aW1 = mfma16(BS(1, ks), hfr[ks], aW1);
        }
      }
      // ---- gates, pack, contiguous 16B sc1 store ----
      unsigned huv[2];
#pragma unroll
      for (int mi = 0; mi < 2; ++mi) {
        float p_i = (mi ? aW1[0] + aI1[0] : aW0[0] + aI0[0]) + bs[mi][0];
        float p_f = (mi ? aW1[1] + aI1[1] : aW0[1] + aI0[1]) + bs[mi][1];
        float p_g = (mi ? aW1[2] + aI1[2] : aW0[2] + aI0[2]) + bs[mi][2];
        float p_o = (mi ? aW1[3] + aI1[3] : aW0[3] + aI0[3]) + bs[mi][3];
        float iv = sigf(p_i);
        float fv = sigf(p_f);
        float gv = tanh_s(p_g);
        float ov = sigf(p_o);
        float cn = fv * cst[mi] + iv * gv;
        cst[mi] = cn;
        huv[mi] = (unsigned)f2bf(ov * tanh_s(cn));
      }
      unsigned p0 = (unsigned)__shfl_xor((int)huv[0], 16);
      unsigned p1 = (unsigned)__shfl_xor((int)huv[1], 16);
      unsigned w0 = huv[0] | (p0 << 16);
      unsigned w1 = huv[1] | (p1 << 16);
      unsigned q0 = (unsigned)__shfl_xor((int)w0, 32);
      unsigned q1 = (unsigned)__shfl_xor((int)w1, 32);
      if (rg == 0) {
        u32x4 v = {w0, q0, w1, q1};
        st16_sc1(h1r + (long)s * 65536 + bid * 512 + b * 8, v);
      }
      asm volatile("s_waitcnt vmcnt(0)" ::: "memory");
      __syncthreads();
      if (tid == 0) ast32(fown + bid, (unsigned)(s + 2));
    }
    // ---- L1 wait export: WRITE channel (block 128 only): bytes = ticks ----
    if (bid == 0 && w == 0) {
      unsigned long long n = wait_acc >> 4;
      if (n > (1ull << 18)) n = 1ull << 18;
      u32x4 v = {0x5a5a5a5au, 0u, 0u, 0u};
      for (unsigned long long i = lane; i < n; i += 64) {
        st16_sc1((char*)instr + (i & 0x3FFFull) * 16, v);
      }
      asm volatile("s_waitcnt vmcnt(0)" ::: "memory");
    }
  }
}

// ---------------------------------------------------------------------------
// emissions: block g handles timestep s=g, all 64 batches. Chunk-layout reads
// are fully coalesced: chunk (g, c=ks*4+rg) holds 64 batches x 16B contiguous.
__global__ __launch_bounds__(256) void emis_k(
    const unsigned short* __restrict__ h1r, const unsigned short* __restrict__ fcw,
    const float* __restrict__ fcb, float* __restrict__ em) {
  __shared__ __align__(16) unsigned short Bsm[32768];
  const int tid = threadIdx.x;
  const int lane = tid & 63;
  const int w = tid >> 6;
  const int c16 = lane & 15, rg = lane >> 4;
  for (int u = tid; u < 4096; u += 256) {
    int tile = u >> 11;
    int ks = (u >> 6) & 31;
    int ln = u & 63;
    int n = tile * 16 + (ln & 15);
    int kb = ks * 32 + (ln >> 4) * 8;
    if (n < 20) {
      *(bf16x8*)&Bsm[u * 8] = *(const bf16x8*)(fcw + (long)n * 1024 + kb);
    } else {
#pragma unroll
      for (int j = 0; j < 8; ++j) Bsm[u * 8 + j] = 0;
    }
  }
  __syncthreads();
  const int g = blockIdx.x;            // timestep
  const int b = w * 16 + c16;          // A-frag row = batch
  const unsigned short* hp = h1r + (long)g * 65536 + rg * 512 + b * 8;
  const f32x4 fz = {0.f, 0.f, 0.f, 0.f};
  f32x4 acc0 = fz, acc1 = fz;
#pragma unroll 4
  for (int ks = 0; ks < 32; ++ks) {
    bf16x8 a = *(const bf16x8*)(hp + ks * 2048);
    acc0 = mfma16(a, *(const bf16x8*)&Bsm[(ks * 64 + lane) * 8], acc0);
    acc1 = mfma16(a, *(const bf16x8*)&Bsm[((32 + ks) * 64 + lane) * 8], acc1);
  }
#pragma unroll
  for (int r = 0; r < 4; ++r) {
    long row = (long)(w * 16 + rg * 4 + r) * 512 + g;   // m = b*512 + s
    em[row * 20 + c16] = acc0[r] + fcb[c16];
    int col1 = 16 + c16;
    if (col1 < 20) em[row * 20 + col1] = acc1[r] + fcb[col1];
  }
}

// ---------------------------------------------------------------------------
// CRF NLL: one wave per batch. Lanes 0..19 hold alpha[j]; 511 serial steps.
__global__ __launch_bounds__(256) void crf_k(
    const float* __restrict__ em, const int* __restrict__ labels,
    const float* __restrict__ startt, const float* __restrict__ endt,
    const float* __restrict__ trans, float* __restrict__ out) {
  const int lane = threadIdx.x & 63;
  const int b = blockIdx.x * 4 + (threadIdx.x >> 6);
  const float NEG = -1e30f;
  const int j = lane;
  const bool act = j < 20;
  float treg[20];
#pragma unroll
  for (int i = 0; i < 20; ++i) treg[i] = act ? trans[i * 20 + j] : 0.f;
  const float* emb = em + (long)b * 512 * 20;
  const int* lab = labels + (long)b * 512;
  float alpha = act ? (startt[j] + emb[j]) : NEG;
  for (int t = 1; t < 512; ++t) {
    float mx = NEG;
#pragma unroll
    for (int i = 0; i < 20; ++i) {
      float v = __shfl(alpha, i) + treg[i];
      mx = fmaxf(mx, v);
    }
    float s = 0.f;
#pragma unroll
    for (int i = 0; i < 20; ++i) {
      float v = __shfl(alpha, i) + treg[i];
      s += __expf(v - mx);
    }
    bool m = lab[t] != -1;
    float na = emb[t * 20 + (act ? j : 0)] + mx + __logf(s);
    if (act && m) alpha = na;
  }
  float v = act ? (alpha + endt[j]) : NEG;
  float mx = v;
#pragma unroll
  for (int o = 32; o > 0; o >>= 1) mx = fmaxf(mx, __shfl_xor(mx, o));
  float s = act ? __expf(v - mx) : 0.f;
#pragma unroll
  for (int o = 32; o > 0; o >>= 1) s += __shfl_xor(s, o);
  float logZ = mx + __logf(s);
  float part = 0.f;
  int cntm = 0;
  for (int t = lane; t < 512; t += 64) cntm += (lab[t] != -1) ? 1 : 0;
  for (int t = 1 + lane; t < 512; t += 64) {
    int tg = lab[t];
    if (tg != -1) {
      int tp = lab[t - 1];
      int tgc = min(max(tg, 0), 19);
      int tpc = min(max(tp, 0), 19);
      part += trans[tpc * 20 + tgc] + emb[t * 20 + tgc];
    }
  }
#pragma unroll
  for (int o = 32; o > 0; o >>= 1) {
    part += __shfl_xor(part, o);
    cntm += __shfl_xor(cntm, o);
  }
  if (lane == 0) {
    int t0c = min(max(lab[0], 0), 19);
    float score = startt[t0c] + emb[t0c] + part;
    int last = max(cntm - 1, 0);
    int tlc = min(max(lab[last], 0), 19);
    score += endt[tlc];
    float llh = score - logZ;
    atomicAdd(out, llh * (-1.f / 64.f));
  }
}

// ---------------------------------------------------------------------------
extern "C" void kernel_launch(void* const* d_in, const int* in_sizes, int n_in,
                              void* d_out, int out_size, void* d_ws, size_t ws_size,
                              hipStream_t stream) {
  const float* x      = (const float*)d_in[0];
  const int* labels   = (const int*)d_in[1];
  const float* Wih0   = (const float*)d_in[3];
  const float* Whh0   = (const float*)d_in[4];
  const float* bih0   = (const float*)d_in[5];
  const float* bhh0   = (const float*)d_in[6];
  const float* Wih1   = (const float*)d_in[7];
  const float* Whh1   = (const float*)d_in[8];
  const float* bih1   = (const float*)d_in[9];
  const float* bhh1   = (const float*)d_in[10];
  const float* fcw    = (const float*)d_in[11];
  const float* fcb    = (const float*)d_in[12];
  const float* startt = (const float*)d_in[13];
  const float* endt   = (const float*)d_in[14];
  const float* trans  = (const float*)d_in[15];
  float* out = (float*)d_out;

  char* ws = (char*)d_ws;
  size_t off = 0;
  auto alloc = [&](size_t bytes) -> void* {
    void* p = ws + off;
    off = (off + bytes + 255) & ~(size_t)255;
    return p;
  };
  unsigned short* h0r    = (unsigned short*)alloc(33554432ull * 2);  // 64 MB
  unsigned short* h1r    = (unsigned short*)alloc(33554432ull * 2);  // 64 MB
  unsigned short* Whh0_b = (unsigned short*)alloc(4194304ull * 2);
  unsigned short* Wih0_b = (unsigned short*)alloc(2097152ull * 2);
  unsigned short* Whh1_b = (unsigned short*)alloc(4194304ull * 2);
  unsigned short* Wih1_b = (unsigned short*)alloc(4194304ull * 2);
  unsigned short* fcw_b  = (unsigned short*)alloc(20480ull * 2);
  float* bias0           = (float*)alloc(4096 * 4);
  float* bias1           = (float*)alloc(4096 * 4);
  float* em              = (float*)alloc(32768ull * 20 * 4);
  unsigned* flags        = (unsigned*)alloc(2048);
  unsigned* instr        = (unsigned*)alloc(1048576);               // 1 MB

  if (off > ws_size) {
    unsigned wsmb = (unsigned)(ws_size >> 20);
    fallback_k<<<1, 1, 0, stream>>>(out, wsmb);
    return;
  }

  // Optional bf16 copy of x (32 MB)
  unsigned short* x_b = nullptr;
  if (off + 33554432ull + 512 <= ws_size) {
    x_b = (unsigned short*)alloc(16777216ull * 2);
  }

  hipMemsetAsync(flags, 0, 2048, stream);
  hipMemsetAsync(d_out, 0, sizeof(float), stream);

  cvt_bf16<<<4096, 256, 0, stream>>>(Whh0, Whh0_b, 4194304);
  cvt_bf16<<<2048, 256, 0, stream>>>(Wih0, Wih0_b, 2097152);
  cvt_bf16<<<4096, 256, 0, stream>>>(Whh1, Whh1_b, 4194304);
  cvt_bf16<<<4096, 256, 0, stream>>>(Wih1, Wih1_b, 4194304);
  cvt_bf16<<<20, 256, 0, stream>>>(fcw, fcw_b, 20480);
  if (x_b) cvt_bf16<<<16384, 256, 0, stream>>>(x, x_b, 16777216);
  add_vec<<<16, 256, 0, stream>>>(bih0, bhh0, bias0, 4096);
  add_vec<<<16, 256, 0, stream>>>(bih1, bhh1, bias1, 4096);

  {
    static bool attr_set = false;   // host-side only; same work every call
    if (!attr_set) {
      hipFuncSetAttribute((const void*)lstm_fused,
                          hipFuncAttributeMaxDynamicSharedMemorySize, 131072);
      attr_set = true;
    }
    void* args[] = {(void*)&x, (void*)&x_b, (void*)&Whh0_b, (void*)&Wih0_b,
                    (void*)&Whh1_b, (void*)&Wih1_b, (void*)&bias0, (void*)&bias1,
                    (void*)&h0r, (void*)&h1r, (void*)&flags, (void*)&instr};
    hipLaunchCooperativeKernel((void*)lstm_fused, dim3(256), dim3(256), args,
                               131072, stream);
  }
  emis_k<<<512, 256, 0, stream>>>(h1r, fcw_b, fcb, em);
  crf_k<<<16, 256, 0, stream>>>(em, labels, startt, endt, trans, out);
}